// Round 3
// baseline (7315.514 us; speedup 1.0000x reference)
//
#include <hip/hip_runtime.h>
#include <hip/hip_bf16.h>
#include <math.h>

#define Bb 32
#define Cc 512
#define NTOK 256
#define HEADS 32
#define DHd 16
#define DEPTH 8
#define FFd 2048
#define NEMB 1024
#define EPSf 1e-5f

__device__ __forceinline__ float gelu_tanh(float x){
    float x3 = x*x*x;
    return 0.5f*x*(1.0f + tanhf(0.7978845608028654f*(x + 0.044715f*x3)));
}

// ---------------- AdaIN + tokenize ----------------
__global__ __launch_bounds__(256) void adain_kernel(const float* __restrict__ cF, const float* __restrict__ sF,
                             const float* __restrict__ pos, float* __restrict__ target,
                             float* __restrict__ x1, float* __restrict__ x2){
    int bc = blockIdx.x;              // b*512 + c
    int n = threadIdx.x;              // spatial token
    float cv = cF[bc*NTOK + n];
    float sv = sF[bc*NTOK + n];
    __shared__ float r1[256], r2[256], r3[256], r4[256];
    r1[n]=cv; r2[n]=cv*cv; r3[n]=sv; r4[n]=sv*sv;
    __syncthreads();
    for (int s=128;s>0;s>>=1){
        if (n<s){ r1[n]+=r1[n+s]; r2[n]+=r2[n+s]; r3[n]+=r3[n+s]; r4[n]+=r4[n+s]; }
        __syncthreads();
    }
    float cm = r1[0]*(1.0f/NTOK);
    float cvar = r2[0]*(1.0f/NTOK) - cm*cm;
    float cs = sqrtf(cvar + EPSf);
    float sm = r3[0]*(1.0f/NTOK);
    float svar = r4[0]*(1.0f/NTOK) - sm*sm;
    float ss = sqrtf(svar + EPSf);
    float tv = ss*(cv-cm)/cs + sm;
    target[bc*NTOK + n] = tv;
    int b = bc >> 9, c = bc & (Cc-1);
    float tok = tv + pos[n*Cc + c];
    x1[(size_t)(b*NTOK + n)*Cc + c] = tok;
    x2[(size_t)(b*NTOK + n)*Cc + c] = tok;
}

// ---------------- shift_half + LayerNorm ----------------
__global__ __launch_bounds__(256) void shift_ln_kernel(const float* __restrict__ x, const float* __restrict__ g,
                                const float* __restrict__ bb, float* __restrict__ h){
    int bn = blockIdx.x;              // b*256 + n
    int n = bn & (NTOK-1);
    int t = threadIdx.x;              // channel t and t+256
    float v0 = (n>0) ? x[(size_t)(bn-1)*Cc + t] : 0.0f;   // first half: shifted token
    float v1 = x[(size_t)bn*Cc + t + 256];                 // second half: current token
    __shared__ float r1[256], r2[256];
    r1[t] = v0+v1; r2[t] = v0*v0 + v1*v1;
    __syncthreads();
    for (int s=128;s>0;s>>=1){ if(t<s){ r1[t]+=r1[t+s]; r2[t]+=r2[t+s]; } __syncthreads(); }
    float m = r1[0]*(1.0f/Cc);
    float var = r2[0]*(1.0f/Cc) - m*m;
    float rs = rsqrtf(var + EPSf);
    h[(size_t)bn*Cc + t]       = (v0-m)*rs*g[t]     + bb[t];
    h[(size_t)bn*Cc + t + 256] = (v1-m)*rs*g[t+256] + bb[t+256];
}

// ---------------- fp32 tiled GEMM, 128(M) x BN(N), 256 threads ----------------
// EPI 0: +bias store; 1: +bias +R; 2: gelu(+bias); 3: dist = bias - 2*acc
// BN=128: 8x8/thread, grid x = Ncol/128.  BN=64: 8x4/thread, grid x = Ncol/64.
template<int EPI, int BN>
__global__ __launch_bounds__(256) void gemm128(const float* __restrict__ A, const float* __restrict__ Bm,
                       const float* __restrict__ bias, const float* __restrict__ R,
                       float* __restrict__ Cm, int K, int Ncol){
    constexpr int NJ = BN/16;          // per-thread n-accumulators (8 or 4)
    __shared__ float As[16][132];      // [k][m], padded
    __shared__ float Bs[16][BN];       // [k][n]
    int t = threadIdx.x;
    int tx = t & 15, ty = t >> 4;
    int m0 = blockIdx.y*128, n0 = blockIdx.x*BN;
    float acc[8][NJ] = {};
    int arow = t >> 2, akq = t & 3;    // A stage: rows arow, arow+64; k-quad akq
    for (int k0=0;k0<K;k0+=16){
        float4 av0 = *(const float4*)&A[(size_t)(m0+arow)*K + k0 + akq*4];
        float4 av1 = *(const float4*)&A[(size_t)(m0+arow+64)*K + k0 + akq*4];
        float4 bv0, bv1;
        if (BN==128){
            int brow = t >> 5, bnq = t & 31;
            bv0 = *(const float4*)&Bm[(size_t)(k0+brow)*Ncol + n0 + bnq*4];
            bv1 = *(const float4*)&Bm[(size_t)(k0+brow+8)*Ncol + n0 + bnq*4];
        } else {
            int brow = t >> 4, bnq = t & 15;
            bv0 = *(const float4*)&Bm[(size_t)(k0+brow)*Ncol + n0 + bnq*4];
        }
        __syncthreads();   // previous iteration's LDS reads complete
        As[akq*4+0][arow] = av0.x;
        As[akq*4+1][arow] = av0.y;
        As[akq*4+2][arow] = av0.z;
        As[akq*4+3][arow] = av0.w;
        As[akq*4+0][arow+64] = av1.x;
        As[akq*4+1][arow+64] = av1.y;
        As[akq*4+2][arow+64] = av1.z;
        As[akq*4+3][arow+64] = av1.w;
        if (BN==128){
            int brow = t >> 5, bnq = t & 31;
            *(float4*)&Bs[brow][bnq*4]   = bv0;
            *(float4*)&Bs[brow+8][bnq*4] = bv1;
        } else {
            int brow = t >> 4, bnq = t & 15;
            *(float4*)&Bs[brow][bnq*4]   = bv0;
        }
        __syncthreads();
        #pragma unroll
        for (int kk=0;kk<16;kk++){
            float4 a0 = *(const float4*)&As[kk][ty*4];
            float4 a1 = *(const float4*)&As[kk][ty*4+64];
            float a[8]={a0.x,a0.y,a0.z,a0.w,a1.x,a1.y,a1.z,a1.w};
            float b[NJ];
            float4 b0 = *(const float4*)&Bs[kk][tx*4];
            b[0]=b0.x; b[1]=b0.y; b[2]=b0.z; b[3]=b0.w;
            if (BN==128){
                float4 b1 = *(const float4*)&Bs[kk][tx*4+64];
                b[4]=b1.x; b[5]=b1.y; b[6]=b1.z; b[7]=b1.w;
            }
            #pragma unroll
            for (int i=0;i<8;i++)
                #pragma unroll
                for (int j=0;j<NJ;j++)
                    acc[i][j] += a[i]*b[j];
        }
    }
    #pragma unroll
    for (int i=0;i<8;i++){
        int row = m0 + ty*4 + (i&3) + ((i>>2)*64);
        #pragma unroll
        for (int h=0; h<NJ/4; h++){
            int col = n0 + tx*4 + h*64;
            float4 b4 = *(const float4*)&bias[col];
            float4 v;
            if (EPI==3){
                v.x = b4.x - 2.0f*acc[i][h*4+0];
                v.y = b4.y - 2.0f*acc[i][h*4+1];
                v.z = b4.z - 2.0f*acc[i][h*4+2];
                v.w = b4.w - 2.0f*acc[i][h*4+3];
            } else {
                v.x = acc[i][h*4+0] + b4.x;
                v.y = acc[i][h*4+1] + b4.y;
                v.z = acc[i][h*4+2] + b4.z;
                v.w = acc[i][h*4+3] + b4.w;
                if (EPI==1){
                    float4 r4 = *(const float4*)&R[(size_t)row*Ncol + col];
                    v.x += r4.x; v.y += r4.y; v.z += r4.z; v.w += r4.w;
                } else if (EPI==2){
                    v.x = gelu_tanh(v.x); v.y = gelu_tanh(v.y);
                    v.z = gelu_tanh(v.z); v.w = gelu_tanh(v.w);
                }
            }
            *(float4*)&Cm[(size_t)row*Ncol + col] = v;
        }
    }
}

// ---------------- causal attention, one block per (b, head) ----------------
__global__ __launch_bounds__(256) void attn_kernel(const float* __restrict__ qkv, float* __restrict__ o){
    int bh = blockIdx.x;
    int b = bh >> 5, hd = bh & 31;
    int i = threadIdx.x;   // query row
    __shared__ float kl[NTOK][17];
    __shared__ float vl[NTOK][17];
    const float* base = qkv + (size_t)(b*NTOK + i)*(3*Cc) + hd*DHd;
    float q[DHd];
    #pragma unroll
    for (int d=0;d<DHd;d++){
        q[d] = base[d] * 0.25f;          // * DH^-0.5
        kl[i][d] = base[Cc + d];
        vl[i][d] = base[2*Cc + d];
    }
    __syncthreads();
    float m = -1e30f, l = 0.0f, acc[DHd] = {};
    for (int j=0;j<=i;j++){              // causal: only j<=i
        float s = 0.0f;
        #pragma unroll
        for (int d=0;d<DHd;d++) s += q[d]*kl[j][d];
        float mn = fmaxf(m, s);
        float sc = __expf(m - mn);
        float p = __expf(s - mn);
        l = l*sc + p;
        #pragma unroll
        for (int d=0;d<DHd;d++) acc[d] = acc[d]*sc + p*vl[j][d];
        m = mn;
    }
    float inv = 1.0f/l;
    float* ob = o + (size_t)(b*NTOK + i)*Cc + hd*DHd;
    #pragma unroll
    for (int d=0;d<DHd;d++) ob[d] = acc[d]*inv;
}

// ---------------- VQ helpers ----------------
__global__ void embed_norm_kernel(const float* __restrict__ embed, float* __restrict__ enorm){
    int j = blockIdx.x*256 + threadIdx.x;
    float s = 0.0f;
    for (int c=0;c<Cc;c++){ float v = embed[(size_t)c*NEMB + j]; s += v*v; }
    enorm[j] = s;
}

__global__ void meanf_kernel(const float* __restrict__ x1, const float* __restrict__ x2, float* __restrict__ f){
    int i = blockIdx.x*256 + threadIdx.x;   // float4 index, total 1048576
    float4 a = ((const float4*)x1)[i];
    float4 b = ((const float4*)x2)[i];
    float4 v; v.x=0.5f*(a.x+b.x); v.y=0.5f*(a.y+b.y); v.z=0.5f*(a.z+b.z); v.w=0.5f*(a.w+b.w);
    ((float4*)f)[i] = v;
}

__global__ __launch_bounds__(256) void argmin_kernel(const float* __restrict__ dist, int* __restrict__ ind,
                              float* __restrict__ ind_out){
    int bn = blockIdx.x;   // pixel
    int t = threadIdx.x;
    const float* dr = dist + (size_t)bn*NEMB;
    float best = dr[t]; int bi = t;
    #pragma unroll
    for (int q=1;q<4;q++){
        int j = t + q*256;
        float c = dr[j];
        if (c < best){ best = c; bi = j; }   // ascending scan: strict < keeps first occurrence
    }
    __shared__ float bv[256]; __shared__ int bidx[256];
    bv[t]=best; bidx[t]=bi;
    __syncthreads();
    for (int s=128;s>0;s>>=1){
        if (t<s){
            if (bv[t+s] < bv[t] || (bv[t+s]==bv[t] && bidx[t+s]<bidx[t])){ bv[t]=bv[t+s]; bidx[t]=bidx[t+s]; }
        }
        __syncthreads();
    }
    if (t==0){ ind[bn] = bidx[0]; ind_out[bn] = (float)bidx[0]; }
}

// ---------------- quant + out + losses ----------------
__global__ __launch_bounds__(256) void quant_loss_kernel(const int* __restrict__ ind, const float* __restrict__ embed,
                                  const float* __restrict__ target, float* __restrict__ out,
                                  float* __restrict__ acc){
    int bc = blockIdx.x;   // b*512 + c
    int b = bc >> 9, c = bc & (Cc-1);
    int n = threadIdx.x;
    int j = ind[b*NTOK + n];
    float q = embed[(size_t)c*NEMB + j];
    float tv = target[(size_t)bc*NTOK + n];
    out[(size_t)bc*NTOK + n] = q;
    __shared__ float r1[256],r2[256],r3[256],r4[256],r5[256];
    float d = q - tv;
    r1[n]=d*d; r2[n]=q; r3[n]=q*q; r4[n]=tv; r5[n]=tv*tv;
    __syncthreads();
    for (int s=128;s>0;s>>=1){
        if(n<s){ r1[n]+=r1[n+s]; r2[n]+=r2[n+s]; r3[n]+=r3[n+s]; r4[n]+=r4[n+s]; r5[n]+=r5[n+s]; }
        __syncthreads();
    }
    if (n==0){
        atomicAdd(acc+0, r1[0]);
        float qm = r2[0]*(1.0f/NTOK);
        float qv = r3[0]*(1.0f/NTOK) - qm*qm;
        float qs = sqrtf(qv + EPSf);
        float tm = r4[0]*(1.0f/NTOK);
        float tvv = r5[0]*(1.0f/NTOK) - tm*tm;
        float ts = sqrtf(tvv + EPSf);
        float dm = qm-tm, dsd = qs-ts;
        atomicAdd(acc+1, dm*dm);
        atomicAdd(acc+2, dsd*dsd);
    }
}

__global__ void final_loss_kernel(const float* __restrict__ acc, float* __restrict__ loss){
    loss[0] = acc[0]*(1.0f/((float)Bb*Cc*NTOK)) + 10.0f*(acc[1]*(1.0f/((float)Bb*Cc)) + acc[2]*(1.0f/((float)Bb*Cc)));
}

extern "C" void kernel_launch(void* const* d_in, const int* in_sizes, int n_in,
                              void* d_out, int out_size, void* d_ws, size_t ws_size,
                              hipStream_t stream){
    const float* cF   = (const float*)d_in[0];
    const float* sF   = (const float*)d_in[1];
    const float* embed= (const float*)d_in[2];
    const float* pos  = (const float*)d_in[3];
    const float* Wqkv = (const float*)d_in[4];
    const float* bqkv = (const float*)d_in[5];
    const float* Wo   = (const float*)d_in[6];
    const float* bo   = (const float*)d_in[7];
    const float* ln1g = (const float*)d_in[8];
    const float* ln1b = (const float*)d_in[9];
    const float* W1   = (const float*)d_in[10];
    const float* b1   = (const float*)d_in[11];
    const float* W2   = (const float*)d_in[12];
    const float* b2   = (const float*)d_in[13];
    const float* ln2g = (const float*)d_in[14];
    const float* ln2b = (const float*)d_in[15];

    float* out = (float*)d_out;                        // quant [B,C,H,W]
    float* ind_out = out + (size_t)Bb*Cc*NTOK;         // embed_ind as float [B,H,W]
    float* loss_out = ind_out + (size_t)Bb*NTOK;       // scalar

    float* ws = (float*)d_ws;
    float* target = ws;                    // 4194304 floats
    float* x1 = ws + 4194304;              // 4194304
    float* x2 = ws + 8388608;              // 4194304
    float* h  = ws + 12582912;             // 4194304
    float* big = ws + 16777216;            // 16777216 floats shared scratch
    float* qkv = big;                      // 8192*1536 = 12582912
    float* o   = big + 12582912;           // 8192*512  = 4194304
    float* ff  = big;                      // 8192*2048 = 16777216
    float* f   = big;                      // 8192*512  = 4194304 (after layers)
    float* dist= big + 4194304;            // 8192*1024 = 8388608
    float* enorm = ws + 33554432;          // 1024
    int*   ind   = (int*)(ws + 33555456);  // 8192
    float* acc   = ws + 33563648;          // 3

    hipMemsetAsync(acc, 0, 3*sizeof(float), stream);

    adain_kernel<<<Bb*Cc, 256, 0, stream>>>(cF, sF, pos, target, x1, x2);

    for (int i=0;i<DEPTH;i++){
        // attention block (reads x2, writes x1)
        shift_ln_kernel<<<Bb*NTOK, 256, 0, stream>>>(x2, ln1g + i*Cc, ln1b + i*Cc, h);
        gemm128<0,128><<<dim3(12,64), 256, 0, stream>>>(h, Wqkv + (size_t)i*Cc*3*Cc, bqkv + (size_t)i*3*Cc, nullptr, qkv, Cc, 3*Cc);
        attn_kernel<<<Bb*HEADS, 256, 0, stream>>>(qkv, o);
        gemm128<1,64><<<dim3(8,64), 256, 0, stream>>>(o, Wo + (size_t)i*Cc*Cc, bo + (size_t)i*Cc, x1, x1, Cc, Cc);
        // feedforward block (reads x1, writes x2)
        shift_ln_kernel<<<Bb*NTOK, 256, 0, stream>>>(x1, ln2g + i*Cc, ln2b + i*Cc, h);
        gemm128<2,128><<<dim3(16,64), 256, 0, stream>>>(h, W1 + (size_t)i*Cc*FFd, b1 + (size_t)i*FFd, nullptr, ff, Cc, FFd);
        gemm128<1,64><<<dim3(8,64), 256, 0, stream>>>(ff, W2 + (size_t)i*FFd*Cc, b2 + (size_t)i*Cc, x2, x2, FFd, Cc);
    }

    // VQ as GEMM: dist = enorm[n] - 2 * f @ embed   (||f||^2 dropped, argmin-invariant)
    embed_norm_kernel<<<NEMB/256, 256, 0, stream>>>(embed, enorm);
    meanf_kernel<<<4096, 256, 0, stream>>>(x1, x2, f);
    gemm128<3,128><<<dim3(8,64), 256, 0, stream>>>(f, embed, enorm, nullptr, dist, Cc, NEMB);
    argmin_kernel<<<Bb*NTOK, 256, 0, stream>>>(dist, ind, ind_out);
    quant_loss_kernel<<<Bb*Cc, 256, 0, stream>>>(ind, embed, target, out, acc);
    final_loss_kernel<<<1,1,0,stream>>>(acc, loss_out);
}

// Round 6
// 3567.743 us; speedup vs baseline: 2.0505x; 2.0505x over previous
//
#include <hip/hip_runtime.h>
#include <hip/hip_bf16.h>
#include <math.h>

#define Bb 32
#define Cc 512
#define NTOK 256
#define HEADS 32
#define DHd 16
#define DEPTH 8
#define FFd 2048
#define NEMB 1024
#define EPSf 1e-5f

typedef _Float16 f16;
typedef _Float16 f16x4 __attribute__((ext_vector_type(4)));
typedef _Float16 f16x8 __attribute__((ext_vector_type(8)));
typedef float f32x4 __attribute__((ext_vector_type(4)));

__device__ __forceinline__ float gelu_tanh(float x){
    float x3 = x*x*x;
    return 0.5f*x*(1.0f + tanhf(0.7978845608028654f*(x + 0.044715f*x3)));
}

// ---------------- AdaIN + tokenize ----------------
__global__ __launch_bounds__(256) void adain_kernel(const float* __restrict__ cF, const float* __restrict__ sF,
                             const float* __restrict__ pos, float* __restrict__ target,
                             float* __restrict__ x1, float* __restrict__ x2){
    int bc = blockIdx.x;              // b*512 + c
    int n = threadIdx.x;              // spatial token
    float cv = cF[bc*NTOK + n];
    float sv = sF[bc*NTOK + n];
    __shared__ float r1[256], r2[256], r3[256], r4[256];
    r1[n]=cv; r2[n]=cv*cv; r3[n]=sv; r4[n]=sv*sv;
    __syncthreads();
    for (int s=128;s>0;s>>=1){
        if (n<s){ r1[n]+=r1[n+s]; r2[n]+=r2[n+s]; r3[n]+=r3[n+s]; r4[n]+=r4[n+s]; }
        __syncthreads();
    }
    float cm = r1[0]*(1.0f/NTOK);
    float cvar = r2[0]*(1.0f/NTOK) - cm*cm;
    float cs = sqrtf(cvar + EPSf);
    float sm = r3[0]*(1.0f/NTOK);
    float svar = r4[0]*(1.0f/NTOK) - sm*sm;
    float ss = sqrtf(svar + EPSf);
    float tv = ss*(cv-cm)/cs + sm;
    target[bc*NTOK + n] = tv;
    int b = bc >> 9, c = bc & (Cc-1);
    float tok = tv + pos[n*Cc + c];
    x1[(size_t)(b*NTOK + n)*Cc + c] = tok;
    x2[(size_t)(b*NTOK + n)*Cc + c] = tok;
}

// ---------------- shift_half + LayerNorm -> f16 hi/lo (lo scaled 2^11) ----------------
__global__ __launch_bounds__(256) void shift_ln_kernel(const float* __restrict__ x, const float* __restrict__ g,
                                const float* __restrict__ bb, f16* __restrict__ hh, f16* __restrict__ hl){
    int bn = blockIdx.x;              // b*256 + n
    int n = bn & (NTOK-1);
    int t = threadIdx.x;              // channel t and t+256
    float v0 = (n>0) ? x[(size_t)(bn-1)*Cc + t] : 0.0f;   // first half: shifted token
    float v1 = x[(size_t)bn*Cc + t + 256];                 // second half: current token
    __shared__ float r1[256], r2[256];
    r1[t] = v0+v1; r2[t] = v0*v0 + v1*v1;
    __syncthreads();
    for (int s=128;s>0;s>>=1){ if(t<s){ r1[t]+=r1[t+s]; r2[t]+=r2[t+s]; } __syncthreads(); }
    float m = r1[0]*(1.0f/Cc);
    float var = r2[0]*(1.0f/Cc) - m*m;
    float rs = rsqrtf(var + EPSf);
    float y0 = (v0-m)*rs*g[t]     + bb[t];
    float y1 = (v1-m)*rs*g[t+256] + bb[t+256];
    size_t base = (size_t)bn*Cc;
    f16 a0 = (f16)y0;
    hh[base + t] = a0;
    hl[base + t] = (f16)((y0 - (float)a0)*2048.0f);
    f16 a1 = (f16)y1;
    hh[base + t + 256] = a1;
    hl[base + t + 256] = (f16)((y1 - (float)a1)*2048.0f);
}

// ---- weight convert: W[K][N] fp32 (row stride Nstr) -> WT[N][K] f16 hi + lo*2^11 ----
__global__ __launch_bounds__(256) void convw_kernel(const float* __restrict__ W, f16* __restrict__ WTh,
                             f16* __restrict__ WTl, int K, int Nstr){
    __shared__ float tile[32][33];
    int t = threadIdx.x;
    int tx = t & 31, ty = t >> 5;              // ty 0..7
    int k0 = blockIdx.y*32, n0 = blockIdx.x*32;
    #pragma unroll
    for (int i=0;i<4;i++)
        tile[ty+8*i][tx] = W[(size_t)(k0+ty+8*i)*Nstr + n0+tx];
    __syncthreads();
    #pragma unroll
    for (int i=0;i<4;i++){
        float v = tile[tx][ty+8*i];
        f16 hi = (f16)v;
        f16 lo = (f16)((v - (float)hi)*2048.0f);   // scale keeps lo normal in f16
        size_t idx = (size_t)(n0+ty+8*i)*K + k0+tx;
        WTh[idx]=hi; WTl[idx]=lo;
    }
}

// ---------------- f16 split-precision MFMA GEMM ----------------
// A,B both pre-split f16 hi/lo, stored [M][K] / [N][K]; lo scaled by 2^11.
// total = Ah*Bh + (Ah*Bl + Al*Bh)*2^-11  -> fp32-class accuracy (f16 products exact in f32 acc)
// EPI 0: C=acc+bias; 1: C=acc+bias+R; 2: Ch/Cl=split(gelu(acc+bias)); 3: C=bias-2*acc; 4: C=acc+R
template<int EPI>
__global__ __launch_bounds__(256,2) void mfma_gemm(const f16* __restrict__ Ah, const f16* __restrict__ Al,
        const f16* __restrict__ Bh, const f16* __restrict__ Bl,
        const float* __restrict__ bias, const float* __restrict__ R,
        float* __restrict__ C, f16* __restrict__ Ch, f16* __restrict__ Cl, int K, int Ncol){
    __shared__ f16 Ash[128][40];   // row stride 80B: 16B-aligned, period-8 bank spread
    __shared__ f16 Asl[128][40];
    __shared__ f16 Bsh[128][40];
    __shared__ f16 Bsl[128][40];
    int t = threadIdx.x;
    int lane = t & 63, wave = t >> 6;
    int wm = wave >> 1, wn = wave & 1;         // 2x2 waves, 64x64 per wave
    int rl = lane & 15, kg = lane >> 4;        // fragment row/col and k-group
    int m0 = blockIdx.y*128, n0 = blockIdx.x*128;
    f32x4 acc1[4][4], acc2[4][4];
    #pragma unroll
    for (int mi=0;mi<4;mi++)
        #pragma unroll
        for (int ni=0;ni<4;ni++){
            acc1[mi][ni] = (f32x4){0.f,0.f,0.f,0.f};
            acc2[mi][ni] = (f32x4){0.f,0.f,0.f,0.f};
        }
    int srow = t >> 1, skh = (t & 1) * 16;     // staging: row 0..127, k-half 0/16
    const f16* ahp = Ah + (size_t)(m0 + srow)*K + skh;
    const f16* alp = Al + (size_t)(m0 + srow)*K + skh;
    const f16* bhp = Bh + (size_t)(n0 + srow)*K + skh;
    const f16* blp = Bl + (size_t)(n0 + srow)*K + skh;
    for (int k0 = 0; k0 < K; k0 += 32){
        float4 va0 = *(const float4*)(ahp + k0);
        float4 va1 = *(const float4*)(ahp + k0 + 8);
        float4 vb0 = *(const float4*)(alp + k0);
        float4 vb1 = *(const float4*)(alp + k0 + 8);
        float4 vc0 = *(const float4*)(bhp + k0);
        float4 vc1 = *(const float4*)(bhp + k0 + 8);
        float4 vd0 = *(const float4*)(blp + k0);
        float4 vd1 = *(const float4*)(blp + k0 + 8);
        __syncthreads();                        // previous compute done before overwrite
        *(float4*)&Ash[srow][skh]   = va0;
        *(float4*)&Ash[srow][skh+8] = va1;
        *(float4*)&Asl[srow][skh]   = vb0;
        *(float4*)&Asl[srow][skh+8] = vb1;
        *(float4*)&Bsh[srow][skh]   = vc0;
        *(float4*)&Bsh[srow][skh+8] = vc1;
        *(float4*)&Bsl[srow][skh]   = vd0;
        *(float4*)&Bsl[srow][skh+8] = vd1;
        __syncthreads();                        // tile ready
        f16x8 ah[4], al[4];
        #pragma unroll
        for (int mi=0;mi<4;mi++){
            ah[mi] = *(const f16x8*)&Ash[wm*64 + mi*16 + rl][kg*8];
            al[mi] = *(const f16x8*)&Asl[wm*64 + mi*16 + rl][kg*8];
        }
        #pragma unroll
        for (int ni=0;ni<4;ni++){
            f16x8 bhf = *(const f16x8*)&Bsh[wn*64 + ni*16 + rl][kg*8];
            f16x8 blf = *(const f16x8*)&Bsl[wn*64 + ni*16 + rl][kg*8];
            #pragma unroll
            for (int mi=0;mi<4;mi++){
                acc1[mi][ni] = __builtin_amdgcn_mfma_f32_16x16x32_f16(ah[mi], bhf, acc1[mi][ni], 0,0,0);
                acc2[mi][ni] = __builtin_amdgcn_mfma_f32_16x16x32_f16(ah[mi], blf, acc2[mi][ni], 0,0,0);
                acc2[mi][ni] = __builtin_amdgcn_mfma_f32_16x16x32_f16(al[mi], bhf, acc2[mi][ni], 0,0,0);
            }
        }
    }
    // epilogue: C/D layout col = lane&15, row = (lane>>4)*4 + reg  (m89-verified)
    float bcol[4];
    if (EPI != 4){
        #pragma unroll
        for (int ni=0;ni<4;ni++) bcol[ni] = bias[n0 + wn*64 + ni*16 + rl];
    }
    #pragma unroll
    for (int ni=0;ni<4;ni++){
        int col = n0 + wn*64 + ni*16 + rl;
        #pragma unroll
        for (int mi=0;mi<4;mi++){
            int row0 = m0 + wm*64 + mi*16 + kg*4;
            #pragma unroll
            for (int j=0;j<4;j++){
                float v = acc1[mi][ni][j] + acc2[mi][ni][j]*(1.0f/2048.0f);
                size_t off = (size_t)(row0 + j)*Ncol + col;
                if (EPI==3){
                    C[off] = bcol[ni] - 2.0f*v;
                } else if (EPI==4){
                    C[off] = v + R[off];
                } else if (EPI==2){
                    float o_ = gelu_tanh(v + bcol[ni]);
                    f16 hv = (f16)o_;
                    Ch[off] = hv;
                    Cl[off] = (f16)((o_ - (float)hv)*2048.0f);
                } else {
                    float o_ = v + bcol[ni];
                    if (EPI==1) o_ += R[off];
                    C[off] = o_;
                }
            }
        }
    }
}

// ---------------- causal attention, one block per (b, head); emits f16 hi/lo ----------------
__global__ __launch_bounds__(256) void attn_kernel(const float* __restrict__ qkv,
                             f16* __restrict__ oh, f16* __restrict__ ol){
    int bh = blockIdx.x;
    int b = bh >> 5, hd = bh & 31;
    int i = threadIdx.x;   // query row
    __shared__ float kl[NTOK][17];
    __shared__ float vl[NTOK][17];
    const float* base = qkv + (size_t)(b*NTOK + i)*(3*Cc) + hd*DHd;
    float q[DHd];
    #pragma unroll
    for (int d=0;d<DHd;d++){
        q[d] = base[d] * 0.25f;          // * DH^-0.5
        kl[i][d] = base[Cc + d];
        vl[i][d] = base[2*Cc + d];
    }
    __syncthreads();
    float m = -1e30f, l = 0.0f, acc[DHd] = {};
    for (int j=0;j<=i;j++){              // causal: only j<=i
        float s = 0.0f;
        #pragma unroll
        for (int d=0;d<DHd;d++) s += q[d]*kl[j][d];
        float mn = fmaxf(m, s);
        float sc = __expf(m - mn);
        float p = __expf(s - mn);
        l = l*sc + p;
        #pragma unroll
        for (int d=0;d<DHd;d++) acc[d] = acc[d]*sc + p*vl[j][d];
        m = mn;
    }
    float inv = 1.0f/l;
    size_t ob = (size_t)(b*NTOK + i)*Cc + hd*DHd;
    #pragma unroll
    for (int d=0;d<DHd;d++){
        float v = acc[d]*inv;
        f16 hv = (f16)v;
        oh[ob + d] = hv;
        ol[ob + d] = (f16)((v - (float)hv)*2048.0f);
    }
}

// ---------------- VQ helpers ----------------
__global__ void embed_norm_kernel(const float* __restrict__ embed, float* __restrict__ enorm){
    int j = blockIdx.x*256 + threadIdx.x;
    float s = 0.0f;
    for (int c=0;c<Cc;c++){ float v = embed[(size_t)c*NEMB + j]; s += v*v; }
    enorm[j] = s;
}

__global__ void meanf_kernel(const float* __restrict__ x1, const float* __restrict__ x2,
                             f16* __restrict__ fh, f16* __restrict__ fl){
    int i = blockIdx.x*256 + threadIdx.x;   // float4 index, total 1048576
    float4 a = ((const float4*)x1)[i];
    float4 b = ((const float4*)x2)[i];
    float v0=0.5f*(a.x+b.x), v1=0.5f*(a.y+b.y), v2=0.5f*(a.z+b.z), v3=0.5f*(a.w+b.w);
    f16x4 hv, lv;
    hv[0]=(f16)v0; lv[0]=(f16)((v0-(float)hv[0])*2048.0f);
    hv[1]=(f16)v1; lv[1]=(f16)((v1-(float)hv[1])*2048.0f);
    hv[2]=(f16)v2; lv[2]=(f16)((v2-(float)hv[2])*2048.0f);
    hv[3]=(f16)v3; lv[3]=(f16)((v3-(float)hv[3])*2048.0f);
    ((f16x4*)fh)[i] = hv;
    ((f16x4*)fl)[i] = lv;
}

__global__ __launch_bounds__(256) void argmin_kernel(const float* __restrict__ dist, int* __restrict__ ind,
                              float* __restrict__ ind_out){
    int bn = blockIdx.x;   // pixel
    int t = threadIdx.x;
    const float* dr = dist + (size_t)bn*NEMB;
    float best = dr[t]; int bi = t;
    #pragma unroll
    for (int q=1;q<4;q++){
        int j = t + q*256;
        float c = dr[j];
        if (c < best){ best = c; bi = j; }   // ascending scan: strict < keeps first occurrence
    }
    __shared__ float bv[256]; __shared__ int bidx[256];
    bv[t]=best; bidx[t]=bi;
    __syncthreads();
    for (int s=128;s>0;s>>=1){
        if (t<s){
            if (bv[t+s] < bv[t] || (bv[t+s]==bv[t] && bidx[t+s]<bidx[t])){ bv[t]=bv[t+s]; bidx[t]=bidx[t+s]; }
        }
        __syncthreads();
    }
    if (t==0){ ind[bn] = bidx[0]; ind_out[bn] = (float)bidx[0]; }
}

// ---------------- quant + out + per-block loss partials (NO atomics) ----------------
__global__ __launch_bounds__(256) void quant_loss_kernel(const int* __restrict__ ind, const float* __restrict__ embed,
                                  const float* __restrict__ target, float* __restrict__ out,
                                  float* __restrict__ part){
    int bc = blockIdx.x;   // b*512 + c
    int b = bc >> 9, c = bc & (Cc-1);
    int n = threadIdx.x;
    int j = ind[b*NTOK + n];
    float q = embed[(size_t)c*NEMB + j];
    float tv = target[(size_t)bc*NTOK + n];
    out[(size_t)bc*NTOK + n] = q;
    __shared__ float r1[256],r2[256],r3[256],r4[256],r5[256];
    float d = q - tv;
    r1[n]=d*d; r2[n]=q; r3[n]=q*q; r4[n]=tv; r5[n]=tv*tv;
    __syncthreads();
    for (int s=128;s>0;s>>=1){
        if(n<s){ r1[n]+=r1[n+s]; r2[n]+=r2[n+s]; r3[n]+=r3[n+s]; r4[n]+=r4[n+s]; r5[n]+=r5[n+s]; }
        __syncthreads();
    }
    if (n==0){
        float qm = r2[0]*(1.0f/NTOK);
        float qv = r3[0]*(1.0f/NTOK) - qm*qm;
        float qs = sqrtf(qv + EPSf);
        float tm = r4[0]*(1.0f/NTOK);
        float tvv = r5[0]*(1.0f/NTOK) - tm*tm;
        float ts = sqrtf(tvv + EPSf);
        float dm = qm-tm, dsd = qs-ts;
        part[bc*3+0] = r1[0];
        part[bc*3+1] = dm*dm;
        part[bc*3+2] = dsd*dsd;
    }
}

__global__ __launch_bounds__(256) void final_loss_kernel(const float* __restrict__ part, float* __restrict__ loss){
    int t = threadIdx.x;
    float s0=0,s1=0,s2=0;
    for (int i=t; i<Bb*Cc; i+=256){ s0+=part[i*3]; s1+=part[i*3+1]; s2+=part[i*3+2]; }
    __shared__ float r0[256],r1[256],r2[256];
    r0[t]=s0; r1[t]=s1; r2[t]=s2;
    __syncthreads();
    for (int s=128;s>0;s>>=1){
        if (t<s){ r0[t]+=r0[t+s]; r1[t]+=r1[t+s]; r2[t]+=r2[t+s]; }
        __syncthreads();
    }
    if (t==0)
        loss[0] = r0[0]*(1.0f/((float)Bb*Cc*NTOK)) + 10.0f*((r1[0]+r2[0])*(1.0f/((float)Bb*Cc)));
}

extern "C" void kernel_launch(void* const* d_in, const int* in_sizes, int n_in,
                              void* d_out, int out_size, void* d_ws, size_t ws_size,
                              hipStream_t stream){
    const float* cF   = (const float*)d_in[0];
    const float* sF   = (const float*)d_in[1];
    const float* embed= (const float*)d_in[2];
    const float* pos  = (const float*)d_in[3];
    const float* Wqkv = (const float*)d_in[4];
    const float* bqkv = (const float*)d_in[5];
    const float* Wo   = (const float*)d_in[6];
    const float* bo   = (const float*)d_in[7];
    const float* ln1g = (const float*)d_in[8];
    const float* ln1b = (const float*)d_in[9];
    const float* W1   = (const float*)d_in[10];
    const float* b1   = (const float*)d_in[11];
    const float* W2   = (const float*)d_in[12];
    const float* b2   = (const float*)d_in[13];
    const float* ln2g = (const float*)d_in[14];
    const float* ln2b = (const float*)d_in[15];

    float* out = (float*)d_out;                        // quant [B,C,H,W]
    float* ind_out = out + (size_t)Bb*Cc*NTOK;         // embed_ind as float [B,H,W]
    float* loss_out = ind_out + (size_t)Bb*NTOK;       // scalar

    // ws layout: 33,554,432 float slots = 134.22 MB total (proven bound from r2 pass)
    float* ws = (float*)d_ws;
    float* target = ws;                      // [0 .. 4.19M)
    float* x1 = ws + 4194304;
    float* x2 = ws + 8388608;
    f16*   hh = (f16*)(ws + 12582912);       // shift_ln output hi (8192*512 f16)
    f16*   hl = (f16*)(ws + 14680064);       // shift_ln output lo
    float* big = ws + 16777216;              // 16,777,216 floats shared scratch
    // attention phase:
    float* qkv  = big;                       // fp32 [8192][1536] = 12,582,912 fl
    f16*   wq_h = (f16*)(big + 12582912);    // Wqkv^T hi (1536*512 f16 = 393,216 fl)
    f16*   wq_l = (f16*)(big + 12976128);    //            lo (ends 13,369,344)
    f16*   oh   = (f16*)(big + 12582912);    // attn out hi (overwrites wq, dead)
    f16*   ol   = (f16*)(big + 14680064);    // attn out lo (ends 16,777,216)
    f16*   wo_h = (f16*)(big);               // Wo^T hi (qkv dead post-attn)
    f16*   wo_l = (f16*)(big + 131072);      //       lo (ends 262,144)
    // feedforward phase:
    f16*   ffh  = (f16*)(big);               // gelu out hi (8192*1024 f16 = 4,194,304 fl)
    f16*   ffl  = (f16*)(big + 4194304);     //          lo (ends 8,388,608)
    f16*   wf_h = (f16*)(big + 12582912);    // W1/W2 chunk^T hi (up to 1024*1024 f16 = 524,288 fl)
    f16*   wf_l = (f16*)(big + 13107200);    //               lo (ends 13,631,488)
    // VQ phase:
    f16*   fh   = (f16*)(big);               // mean-f hi (4,194,304 f16 = 2,097,152 fl)
    f16*   fl_  = (f16*)(big + 2097152);     //        lo (ends 4,194,304)
    float* dist = big + 4194304;             // fp32 [8192][1024] (ends 12,582,912)
    f16*   we_h = (f16*)(big + 12582912);    // embed^T hi (1024*512 f16 = 262,144 fl)
    f16*   we_l = (f16*)(big + 12845056);    //          lo (ends 13,107,200)
    // VQ-tail small buffers in the hh/hl region (dead after last layer):
    float* enorm = ws + 12582912;            // 1024
    int*   ind   = (int*)(ws + 12583936);    // 8192 ints
    float* part  = ws + 12599296;            // 49,152 floats

    adain_kernel<<<Bb*Cc, 256, 0, stream>>>(cF, sF, pos, target, x1, x2);

    for (int i=0;i<DEPTH;i++){
        const float* W1i = W1 + (size_t)i*Cc*FFd;
        const float* W2i = W2 + (size_t)i*FFd*Cc;
        // ---- attention block (reads x2, writes x1) ----
        shift_ln_kernel<<<Bb*NTOK, 256, 0, stream>>>(x2, ln1g + i*Cc, ln1b + i*Cc, hh, hl);
        convw_kernel<<<dim3(48,16), 256, 0, stream>>>(Wqkv + (size_t)i*Cc*3*Cc, wq_h, wq_l, Cc, 3*Cc);
        mfma_gemm<0><<<dim3(12,64), 256, 0, stream>>>(hh, hl, wq_h, wq_l, bqkv + (size_t)i*3*Cc, nullptr, qkv, nullptr, nullptr, Cc, 3*Cc);
        attn_kernel<<<Bb*HEADS, 256, 0, stream>>>(qkv, oh, ol);   // overwrites wq (consumed)
        convw_kernel<<<dim3(16,16), 256, 0, stream>>>(Wo + (size_t)i*Cc*Cc, wo_h, wo_l, Cc, Cc);  // qkv dead
        mfma_gemm<1><<<dim3(4,64), 256, 0, stream>>>(oh, ol, wo_h, wo_l, bo + (size_t)i*Cc, x1, x1, nullptr, nullptr, Cc, Cc);
        // ---- feedforward block (reads x1, writes x2), two K/N=1024 chunks ----
        shift_ln_kernel<<<Bb*NTOK, 256, 0, stream>>>(x1, ln2g + i*Cc, ln2b + i*Cc, hh, hl);
        // chunk a: cols 0..1023 of W1, rows 0..1023 of W2; bias b2 added here
        convw_kernel<<<dim3(32,16), 256, 0, stream>>>(W1i, wf_h, wf_l, Cc, FFd);
        mfma_gemm<2><<<dim3(8,64), 256, 0, stream>>>(hh, hl, wf_h, wf_l, b1 + (size_t)i*FFd, nullptr, nullptr, ffh, ffl, Cc, FFd/2);
        convw_kernel<<<dim3(16,32), 256, 0, stream>>>(W2i, wf_h, wf_l, FFd/2, Cc);
        mfma_gemm<1><<<dim3(4,64), 256, 0, stream>>>(ffh, ffl, wf_h, wf_l, b2 + (size_t)i*Cc, x2, x2, nullptr, nullptr, FFd/2, Cc);
        // chunk b: cols 1024..2047 of W1, rows 1024..2047 of W2; no bias (EPI 4)
        convw_kernel<<<dim3(32,16), 256, 0, stream>>>(W1i + FFd/2, wf_h, wf_l, Cc, FFd);
        mfma_gemm<2><<<dim3(8,64), 256, 0, stream>>>(hh, hl, wf_h, wf_l, b1 + (size_t)i*FFd + FFd/2, nullptr, nullptr, ffh, ffl, Cc, FFd/2);
        convw_kernel<<<dim3(16,32), 256, 0, stream>>>(W2i + (size_t)(FFd/2)*Cc, wf_h, wf_l, FFd/2, Cc);
        mfma_gemm<4><<<dim3(4,64), 256, 0, stream>>>(ffh, ffl, wf_h, wf_l, nullptr, x2, x2, nullptr, nullptr, FFd/2, Cc);
    }

    // ---- VQ: dist = enorm[n] - 2 * f @ embed  (||f||^2 dropped, argmin-invariant) ----
    embed_norm_kernel<<<NEMB/256, 256, 0, stream>>>(embed, enorm);
    meanf_kernel<<<4096, 256, 0, stream>>>(x1, x2, fh, fl_);
    convw_kernel<<<dim3(32,16), 256, 0, stream>>>(embed, we_h, we_l, Cc, NEMB);
    mfma_gemm<3><<<dim3(8,64), 256, 0, stream>>>(fh, fl_, we_h, we_l, enorm, nullptr, dist, nullptr, nullptr, Cc, NEMB);
    argmin_kernel<<<Bb*NTOK, 256, 0, stream>>>(dist, ind, ind_out);
    quant_loss_kernel<<<Bb*Cc, 256, 0, stream>>>(ind, embed, target, out, part);
    final_loss_kernel<<<1,256,0,stream>>>(part, loss_out);
}